// Round 1
// baseline (35.322 us; speedup 1.0000x reference)
//
#include <hip/hip_runtime.h>
#include <math.h>

#define F 24
#define D 16
#define BATCH 2048
#define NPAIR 276
#define NTRIP 2024
#define ROWS_PER_BLOCK 4
#define VOCAB 10000

// pairs before (i,j) in lexicographic combinations(24,2)
__device__ __forceinline__ int pair_idx(int i, int j) {
    return i * 23 - i * (i - 1) / 2 + (j - i - 1);
}
// trips with first index < i: 2024 - C(24-i,3)
__device__ __forceinline__ int trip_base(int i) {
    return NTRIP - (24 - i) * (23 - i) * (22 - i) / 6;
}
// trips before (i,j,k) in lexicographic combinations(24,3)
__device__ __forceinline__ int trip_idx(int i, int j, int k) {
    return trip_base(i) + (j - i - 1) * (46 - i - j) / 2 + (k - j - 1);
}

// Fully-unrolled chunk: pairs with outer index i in [I0, I1).
// All e[] indices are compile-time after unroll -> registers.
template <int I0, int I1>
__device__ __forceinline__ float chunk_compute(const float (&e)[F],
                                               const float* s_g2,
                                               const float* s_g3) {
    float acc = 0.f;
#pragma unroll
    for (int i = I0; i < I1; ++i) {
#pragma unroll
        for (int j = i + 1; j < F; ++j) {
            float pij = e[i] * e[j];
            acc = fmaf(s_g2[pair_idx(i, j)], pij, acc);   // 2nd-order term
            float s = 0.f;
#pragma unroll
            for (int k = j + 1; k < F; ++k)               // contiguous trip ids
                s = fmaf(s_g3[trip_idx(i, j, k)], e[k], s);
            acc = fmaf(pij, s, acc);                      // 3rd-order term
        }
    }
    return acc;
}

__global__ __launch_bounds__(256) void ctr_kernel(
    const int* __restrict__ x,          // [B, F] int32
    const float* __restrict__ emb,      // [240000, 16]
    const float* __restrict__ lw,       // [240000]
    const float* __restrict__ lb,       // [1]
    const float* __restrict__ g2,       // [276]
    const float* __restrict__ g3,       // [2024]
    float* __restrict__ out)            // [B]
{
    __shared__ float s_g2[NPAIR];
    __shared__ float s_g3[NTRIP];
    __shared__ int   s_idx[ROWS_PER_BLOCK * F];
    __shared__ float s_lw[ROWS_PER_BLOCK * F];
    __shared__ float s_part[ROWS_PER_BLOCK][4];

    const int tid = threadIdx.x;
    const int row0 = blockIdx.x * ROWS_PER_BLOCK;

    // ---- stage genotypes + indices + linear-weight gathers into LDS ----
    for (int t = tid; t < NTRIP; t += 256) s_g3[t] = g3[t];
    for (int t = tid; t < NPAIR; t += 256) s_g2[t] = g2[t];
    for (int t = tid; t < ROWS_PER_BLOCK * F; t += 256) {
        int r = t / F, f = t - r * F;
        int idx = x[(row0 + r) * F + f] + f * VOCAB;
        s_idx[t] = idx;
        s_lw[t]  = lw[idx];
    }
    __syncthreads();

    const int d = tid & 15;          // embedding dim lane
    const int r = (tid >> 4) & 3;    // row within block
    const int w = tid >> 6;          // wave id = trip chunk (wave-uniform)

    // ---- gather this row's 24 embedding components at dim d ----
    float e[F];
#pragma unroll
    for (int f = 0; f < F; ++f)
        e[f] = emb[s_idx[r * F + f] * D + d];

    // ---- per-wave static chunk (balanced by trip count) ----
    float acc;
    if (w == 0)      acc = chunk_compute<0, 2>(e, s_g2, s_g3);
    else if (w == 1) acc = chunk_compute<2, 5>(e, s_g2, s_g3);
    else if (w == 2) acc = chunk_compute<5, 9>(e, s_g2, s_g3);
    else             acc = chunk_compute<9, 23>(e, s_g2, s_g3);

    // ---- reduce over the 16 d-lanes (stays within 16-lane subgroup) ----
#pragma unroll
    for (int m = 1; m < 16; m <<= 1)
        acc += __shfl_xor(acc, m, 64);

    if (d == 0) s_part[r][w] = acc;
    __syncthreads();

    // ---- final combine: one thread per row ----
    if (tid < ROWS_PER_BLOCK) {
        float t3 = s_part[tid][0] + s_part[tid][1] + s_part[tid][2] + s_part[tid][3];
        float lin = lb[0];
#pragma unroll
        for (int f = 0; f < F; ++f) lin += s_lw[tid * F + f];
        float z = lin + t3;
        out[row0 + tid] = 1.f / (1.f + __expf(-z));
    }
}

extern "C" void kernel_launch(void* const* d_in, const int* in_sizes, int n_in,
                              void* d_out, int out_size, void* d_ws, size_t ws_size,
                              hipStream_t stream) {
    const int*   x   = (const int*)d_in[0];
    const float* emb = (const float*)d_in[1];
    const float* lw  = (const float*)d_in[2];
    const float* lb  = (const float*)d_in[3];
    const float* g2  = (const float*)d_in[4];
    const float* g3  = (const float*)d_in[5];
    float* out = (float*)d_out;

    hipLaunchKernelGGL(ctr_kernel, dim3(BATCH / ROWS_PER_BLOCK), dim3(256), 0, stream,
                       x, emb, lw, lb, g2, g3, out);
}

// Round 2
// 22.157 us; speedup vs baseline: 1.5942x; 1.5942x over previous
//
#include <hip/hip_runtime.h>
#include <math.h>

#define F 24
#define D 16
#define BATCH 2048
#define NPAIR 276
#define NTRIP 2024
#define VOCAB 10000

// ---- compile-time index algebra for lexicographic combinations ----
__host__ __device__ constexpr int pair_base(int i) { return i * 23 - i * (i - 1) / 2; }
__host__ __device__ constexpr int pair_idx(int i, int j) { return pair_base(i) + (j - i - 1); }
__host__ __device__ constexpr int trip_base(int i) {
    return NTRIP - (24 - i) * (23 - i) * (22 - i) / 6;
}
__host__ __device__ constexpr int trip_idx(int i, int j, int k) {
    return trip_base(i) + (j - i - 1) * (46 - i - j) / 2 + (k - j - 1);
}
__host__ __device__ constexpr int pi_of(int p) {  // i of pair index p
    int i = 0;
    while (pair_base(i + 1) <= p) ++i;
    return i;
}

// 16 contiguous pair-index chunks, balanced by trip count (~126 trips each)
constexpr int CHUNK_B[17] = {0, 7, 23, 30, 46, 54, 70, 86, 95, 111, 127, 143, 160, 179, 201, 227, 276};

// One chunk: pairs p in [CHUNK_B[C], CHUNK_B[C+1]). All e[]/coef indices are
// compile-time after unroll -> e[] in VGPRs, g2/g3 reads are uniform-address
// global loads with literal offsets -> scalar (s_load) candidates.
template <int C>
__device__ __forceinline__ float chunk_compute(const int* sidx,
                                               const float* __restrict__ emb,
                                               int d,
                                               const float* __restrict__ g2,
                                               const float* __restrict__ g3) {
    constexpr int P0 = CHUNK_B[C], P1 = CHUNK_B[C + 1];
    constexpr int IMIN = pi_of(P0);
    constexpr int IMAX = pi_of(P1 - 1);
    float e[F];
#pragma unroll
    for (int f = IMIN; f < F; ++f) e[f] = emb[sidx[f] * D + d];
    float acc = 0.f;
#pragma unroll
    for (int i = IMIN; i <= IMAX; ++i) {
#pragma unroll
        for (int j = i + 1; j < F; ++j) {
            if (pair_idx(i, j) >= P0 && pair_idx(i, j) < P1) {   // folds at compile time
                float pij = e[i] * e[j];
                acc = fmaf(g2[pair_idx(i, j)], pij, acc);        // 2nd-order
                float s = 0.f;
#pragma unroll
                for (int k = j + 1; k < F; ++k)                  // contiguous trip ids
                    s = fmaf(g3[trip_idx(i, j, k)], e[k], s);
                acc = fmaf(pij, s, acc);                         // 3rd-order
            }
        }
    }
    return acc;
}

// Block = 256 thr = 4 rows x 16 d-lanes x 4 waves; each wave owns one of 16
// chunks (cg = blockIdx&3 picks the group of 4) -> wave-uniform dispatch.
__global__ __launch_bounds__(256, 4) void ctr_partial(
    const int* __restrict__ x, const float* __restrict__ emb,
    const float* __restrict__ lw, const float* __restrict__ g2,
    const float* __restrict__ g3, float* __restrict__ ws) {
    __shared__ int   s_idx[4 * F];
    __shared__ float s_lw[4 * F];
    __shared__ float s_part[4][4];

    const int tid = threadIdx.x;
    const int rg = blockIdx.x >> 2, cg = blockIdx.x & 3;
    const int row0 = rg * 4;

    for (int t = tid; t < 4 * F; t += 256) {
        int r = t / F, f = t - r * F;
        int idx = x[(row0 + r) * F + f] + f * VOCAB;
        s_idx[t] = idx;
        if (cg == 0) s_lw[t] = lw[idx];     // linear term folded into cg==0 partial
    }
    __syncthreads();

    const int d = tid & 15;
    const int r = (tid >> 4) & 3;
    const int w = tid >> 6;
    const int c = cg * 4 + w;               // wave-uniform chunk id
    const int* sr = &s_idx[r * F];

    float acc;
    switch (c) {
        case 0:  acc = chunk_compute<0>(sr, emb, d, g2, g3); break;
        case 1:  acc = chunk_compute<1>(sr, emb, d, g2, g3); break;
        case 2:  acc = chunk_compute<2>(sr, emb, d, g2, g3); break;
        case 3:  acc = chunk_compute<3>(sr, emb, d, g2, g3); break;
        case 4:  acc = chunk_compute<4>(sr, emb, d, g2, g3); break;
        case 5:  acc = chunk_compute<5>(sr, emb, d, g2, g3); break;
        case 6:  acc = chunk_compute<6>(sr, emb, d, g2, g3); break;
        case 7:  acc = chunk_compute<7>(sr, emb, d, g2, g3); break;
        case 8:  acc = chunk_compute<8>(sr, emb, d, g2, g3); break;
        case 9:  acc = chunk_compute<9>(sr, emb, d, g2, g3); break;
        case 10: acc = chunk_compute<10>(sr, emb, d, g2, g3); break;
        case 11: acc = chunk_compute<11>(sr, emb, d, g2, g3); break;
        case 12: acc = chunk_compute<12>(sr, emb, d, g2, g3); break;
        case 13: acc = chunk_compute<13>(sr, emb, d, g2, g3); break;
        case 14: acc = chunk_compute<14>(sr, emb, d, g2, g3); break;
        default: acc = chunk_compute<15>(sr, emb, d, g2, g3); break;
    }

    // reduce over the 16 d-lanes (bits 0..3 of lane id)
#pragma unroll
    for (int m = 1; m < 16; m <<= 1) acc += __shfl_xor(acc, m, 64);

    if (d == 0) s_part[r][w] = acc;
    __syncthreads();

    if (tid < 4) {
        float v = (s_part[tid][0] + s_part[tid][1]) + (s_part[tid][2] + s_part[tid][3]);
        if (cg == 0) {
            float lin = 0.f;
#pragma unroll
            for (int f = 0; f < F; ++f) lin += s_lw[tid * F + f];
            v += lin;
        }
        ws[(row0 + tid) * 4 + cg] = v;
    }
}

__global__ __launch_bounds__(256) void ctr_final(const float* __restrict__ ws,
                                                 const float* __restrict__ lb,
                                                 float* __restrict__ out) {
    const int row = blockIdx.x * 256 + threadIdx.x;
    const float4 p = reinterpret_cast<const float4*>(ws)[row];
    const float z = (p.x + p.y) + (p.z + p.w) + lb[0];
    out[row] = 1.f / (1.f + __expf(-z));
}

extern "C" void kernel_launch(void* const* d_in, const int* in_sizes, int n_in,
                              void* d_out, int out_size, void* d_ws, size_t ws_size,
                              hipStream_t stream) {
    const int*   x   = (const int*)d_in[0];
    const float* emb = (const float*)d_in[1];
    const float* lw  = (const float*)d_in[2];
    const float* lb  = (const float*)d_in[3];
    const float* g2  = (const float*)d_in[4];
    const float* g3  = (const float*)d_in[5];
    float* out = (float*)d_out;
    float* ws  = (float*)d_ws;   // 2048 rows x 4 chunk-group partials = 32 KB

    hipLaunchKernelGGL(ctr_partial, dim3(BATCH / 4 * 4), dim3(256), 0, stream,
                       x, emb, lw, g2, g3, ws);
    hipLaunchKernelGGL(ctr_final, dim3(BATCH / 256), dim3(256), 0, stream,
                       ws, lb, out);
}

// Round 3
// 21.172 us; speedup vs baseline: 1.6683x; 1.0465x over previous
//
#include <hip/hip_runtime.h>
#include <math.h>

#define F 24
#define D 16
#define BATCH 2048
#define NPAIR 276
#define NTRIP 2024
#define VOCAB 10000
#define EPAD 17   // padded d-stride: 2-way LDS bank alias max (free)

// ---- compile-time index algebra for lexicographic combinations ----
__host__ __device__ constexpr int pair_base(int i) { return i * 23 - i * (i - 1) / 2; }
__host__ __device__ constexpr int pair_idx(int i, int j) { return pair_base(i) + (j - i - 1); }
__host__ __device__ constexpr int trip_base(int i) {
    return NTRIP - (24 - i) * (23 - i) * (22 - i) / 6;
}
__host__ __device__ constexpr int trip_idx(int i, int j, int k) {
    return trip_base(i) + (j - i - 1) * (46 - i - j) / 2 + (k - j - 1);
}
__host__ __device__ constexpr int pi_of(int p) {  // i of pair index p
    int i = 0;
    while (pair_base(i + 1) <= p) ++i;
    return i;
}

// 16 contiguous pair-index chunks, balanced by trip count (~126 each)
constexpr int CHUNK_B[17] = {0, 7, 23, 30, 46, 54, 70, 86, 95, 111, 127, 143, 160, 179, 201, 227, 276};

// One chunk: pairs p in [CHUNK_B[C], CHUNK_B[C+1]). Everything unrolls;
// e[] lives in VGPRs, g2/g3 reads are uniform-address + literal offset
// -> scalar loads on the SMEM pipe.
template <int C>
__device__ __forceinline__ float chunk_compute(const float* se,   // &s_emb[r][0][d]
                                               const float* __restrict__ g2,
                                               const float* __restrict__ g3) {
    constexpr int P0 = CHUNK_B[C], P1 = CHUNK_B[C + 1];
    constexpr int IMIN = pi_of(P0);
    constexpr int IMAX = pi_of(P1 - 1);
    float e[F];
#pragma unroll
    for (int f = IMIN; f < F; ++f) e[f] = se[f * EPAD];
    float acc = 0.f;
#pragma unroll
    for (int i = IMIN; i <= IMAX; ++i) {
#pragma unroll
        for (int j = i + 1; j < F; ++j) {
            if (pair_idx(i, j) >= P0 && pair_idx(i, j) < P1) {   // folds at compile time
                float pij = e[i] * e[j];
                acc = fmaf(g2[pair_idx(i, j)], pij, acc);        // 2nd-order
                float s = 0.f;
#pragma unroll
                for (int k = j + 1; k < F; ++k)                  // contiguous trip ids
                    s = fmaf(g3[trip_idx(i, j, k)], e[k], s);
                acc = fmaf(pij, s, acc);                         // 3rd-order
            }
        }
    }
    return acc;
}

// Block = 1024 thr = 16 waves. Wave w owns chunk w (wave-uniform switch) for
// all 4 rows of the block: lane = d (0..15) x r (0..3). Embeddings staged in
// LDS once per block; whole row finished in-block (single kernel launch).
__global__ __launch_bounds__(1024) void ctr_kernel(
    const int* __restrict__ x, const float* __restrict__ emb,
    const float* __restrict__ lw, const float* __restrict__ lb,
    const float* __restrict__ g2, const float* __restrict__ g3,
    float* __restrict__ out) {
    __shared__ float s_emb[4][F][EPAD];
    __shared__ float s_lw[4 * F];
    __shared__ float s_part[4][16];

    const int tid = threadIdx.x;
    const int row0 = blockIdx.x * 4;

    // ---- stage 4 rows x 24 fields x 16 dims into LDS (coalesced 64B segs) ----
    for (int t = tid; t < 4 * F * D; t += 1024) {
        int d = t & 15, seg = t >> 4;
        int f = seg % F, r = seg / F;
        int idx = x[(row0 + r) * F + f] + f * VOCAB;
        s_emb[r][f][d] = emb[idx * D + d];
    }
    for (int t = tid; t < 4 * F; t += 1024) {   // linear-weight gather
        int f = t % F, r = t / F;
        s_lw[t] = lw[x[(row0 + r) * F + f] + f * VOCAB];
    }
    __syncthreads();

    const int d = tid & 15;
    const int r = (tid >> 4) & 3;
    const int w = tid >> 6;                     // wave id = chunk id (uniform)
    const float* se = &s_emb[r][0][d];

    float acc;
    switch (w) {
        case 0:  acc = chunk_compute<0>(se, g2, g3); break;
        case 1:  acc = chunk_compute<1>(se, g2, g3); break;
        case 2:  acc = chunk_compute<2>(se, g2, g3); break;
        case 3:  acc = chunk_compute<3>(se, g2, g3); break;
        case 4:  acc = chunk_compute<4>(se, g2, g3); break;
        case 5:  acc = chunk_compute<5>(se, g2, g3); break;
        case 6:  acc = chunk_compute<6>(se, g2, g3); break;
        case 7:  acc = chunk_compute<7>(se, g2, g3); break;
        case 8:  acc = chunk_compute<8>(se, g2, g3); break;
        case 9:  acc = chunk_compute<9>(se, g2, g3); break;
        case 10: acc = chunk_compute<10>(se, g2, g3); break;
        case 11: acc = chunk_compute<11>(se, g2, g3); break;
        case 12: acc = chunk_compute<12>(se, g2, g3); break;
        case 13: acc = chunk_compute<13>(se, g2, g3); break;
        case 14: acc = chunk_compute<14>(se, g2, g3); break;
        default: acc = chunk_compute<15>(se, g2, g3); break;
    }

    // reduce over the 16 d-lanes
#pragma unroll
    for (int m = 1; m < 16; m <<= 1) acc += __shfl_xor(acc, m, 64);
    if (d == 0) s_part[r][w] = acc;
    __syncthreads();

    // ---- final combine: wave 0, conflict-free s_part reads ----
    if (tid < 64) {
        const int rr = tid >> 4, c = tid & 15;
        float v = s_part[rr][c];
#pragma unroll
        for (int m = 1; m < 16; m <<= 1) v += __shfl_xor(v, m, 64);
        if (c == 0) {
            float lin = lb[0];
#pragma unroll
            for (int f = 0; f < F; ++f) lin += s_lw[rr * F + f];
            float z = v + lin;
            out[row0 + rr] = 1.f / (1.f + __expf(-z));
        }
    }
}

extern "C" void kernel_launch(void* const* d_in, const int* in_sizes, int n_in,
                              void* d_out, int out_size, void* d_ws, size_t ws_size,
                              hipStream_t stream) {
    const int*   x   = (const int*)d_in[0];
    const float* emb = (const float*)d_in[1];
    const float* lw  = (const float*)d_in[2];
    const float* lb  = (const float*)d_in[3];
    const float* g2  = (const float*)d_in[4];
    const float* g3  = (const float*)d_in[5];
    float* out = (float*)d_out;

    hipLaunchKernelGGL(ctr_kernel, dim3(BATCH / 4), dim3(1024), 0, stream,
                       x, emb, lw, lb, g2, g3, out);
}